// Round 8
// baseline (272.722 us; speedup 1.0000x reference)
//
#include <hip/hip_runtime.h>
#include <math.h>

// Problem constants (GPT2 decode attention, fp32)
#define BATCH   32
#define NH      16
#define HD      64      // head dim
#define T_ALL   2048    // cached 2047 + 1 new
#define T_CACHE 2047
#define HID     1024
#define H3      3072
#define QK_SCALE 0.125f // 64^-0.5
#define NCHUNK  32      // token chunks per (b,h); one chunk per 4-wave block
#define CHTOK   64      // tokens per chunk (16 per wave)
#define NWIN    4       // 4-token windows per wave (16 tokens/wave)
#define KSPLIT  8       // k-split for the GEMV kernels

// native 16B vector
typedef float f4 __attribute__((ext_vector_type(4)));

// ---------------------------------------------------------------------------
// GEMV part: out_part[ks][b][c] = sum_{k in split ks} X[b][k] * W[k][c]
// batch split across blockIdx.z; per-column k-order unchanged -> bit-exact.
// ---------------------------------------------------------------------------
template<int NB>
__global__ __launch_bounds__(256) void gemv_part_kernel(
    const float* __restrict__ X, const float* __restrict__ W,
    float* __restrict__ part, int N, int Kdim)
{
    const int c  = blockIdx.x * 256 + threadIdx.x;
    const int ks = blockIdx.y;
    const int b0 = blockIdx.z * NB;
    const int kchunk = Kdim / KSPLIT;
    float acc[NB];
#pragma unroll
    for (int j = 0; j < NB; ++j) acc[j] = 0.f;
    const int k0 = ks * kchunk;
#pragma unroll 16
    for (int k = k0; k < k0 + kchunk; ++k) {
        const float w = W[(size_t)k * N + c];
#pragma unroll
        for (int j = 0; j < NB; ++j)
            acc[j] = fmaf(X[(b0 + j) * Kdim + k], w, acc[j]);
    }
#pragma unroll
    for (int j = 0; j < NB; ++j)
        part[((size_t)ks * BATCH + b0 + j) * N + c] = acc[j];
}

// float4 reduce (bit-exact per element: bias first, then ks ascending)
__global__ __launch_bounds__(256) void gemv_reduce_kernel(
    const float* __restrict__ part, const float* __restrict__ bias,
    float* __restrict__ out, int N)
{
    const int c4 = blockIdx.x * 256 + threadIdx.x;
    const int b  = blockIdx.y;
    const int N4 = N >> 2;
    f4 acc = ((const f4*)bias)[c4];
#pragma unroll
    for (int ks = 0; ks < KSPLIT; ++ks) {
        const f4 p = ((const f4*)part)[((size_t)ks * BATCH + b) * N4 + c4];
        acc.x += p.x; acc.y += p.y; acc.z += p.z; acc.w += p.w;
    }
    ((f4*)out)[(size_t)b * N4 + c4] = acc;
}

// ---------------------------------------------------------------------------
// Fused cache-copy + flash-decoding attention, v8.
// Identical to v6 (round-5 best, 243.2 us) EXCEPT: all nontemporal
// load/store hints removed — plain f4 accesses so the L2 aggregates the
// stream like the 6.3-6.8 TB/s reference copy/fill kernels do.
// grid = (NCHUNK=32, NH, BATCH) = 16384 blocks, block = 256 (4 waves).
// Wave owns 16 tokens = 4 windows (4 tokens x 16 f4-groups).
// ---------------------------------------------------------------------------
__global__ __launch_bounds__(256, 6) void fused_copy_attn_kernel(
    const float* __restrict__ kc, const float* __restrict__ vc,
    const float* __restrict__ qkv_part, const float* __restrict__ b_attn,
    const int* __restrict__ seq_lens,
    float* __restrict__ Kout, float* __restrict__ Vout,
    float* __restrict__ Pm, float* __restrict__ Pl, float* __restrict__ Po)
{
    const int chunk = blockIdx.x;
    const int h     = blockIdx.y;
    const int b     = blockIdx.z;
    const int tid   = threadIdx.x;
    const int wave  = tid >> 6;
    const int lane  = tid & 63;
    const int dgrp  = lane & 15;   // which float4 of the 64-dim row
    const int tgrp  = lane >> 4;   // which of 4 tokens per window

    const int bh   = b * NH + h;
    const int slen = seq_lens[b];

    // q = b_attn + sum_ks qkv_part  (bit-identical to the removed reduce)
    f4 q4 = ((const f4*)(b_attn + h * HD))[dgrp];
#pragma unroll
    for (int ks = 0; ks < KSPLIT; ++ks) {
        const f4 p = ((const f4*)(qkv_part + ((size_t)ks * BATCH + b) * H3 + h * HD))[dgrp];
        q4.x += p.x; q4.y += p.y; q4.z += p.z; q4.w += p.w;
    }

    const int t0 = chunk * CHTOK + wave * (NWIN * 4);
    const int tl = t0 + tgrp;                       // this lane's first token
    const int nat  = min(NWIN, max(0, (slen - t0 + 3) >> 2));
    const bool tail = (t0 + NWIN * 4 - 1 >= T_CACHE);  // single tail wave

    const f4* kbase = (const f4*)(kc + (size_t)bh * T_CACHE * HD) + (size_t)tl * 16 + dgrp;
    const f4* vbase = (const f4*)(vc + (size_t)bh * T_CACHE * HD) + (size_t)tl * 16 + dgrp;
    f4* Kb = (f4*)(Kout + (size_t)bh * T_ALL * HD) + (size_t)tl * 16 + dgrp;
    f4* Vb = (f4*)(Vout + (size_t)bh * T_ALL * HD) + (size_t)tl * 16 + dgrp;

    f4 kreg[NWIN], vreg[NWIN];
    float s[NWIN];

    if (!tail) {
        // ---- issue ALL loads upfront: 8 in flight per wave ---------------
#pragma unroll
        for (int i = 0; i < NWIN; ++i)
            kreg[i] = kbase[i * 64];
#pragma unroll
        for (int i = 0; i < NWIN; ++i)
            vreg[i] = vbase[i * 64];

        // ---- K: store + scores (V loads still in flight) -----------------
#pragma unroll
        for (int i = 0; i < NWIN; ++i) {
            Kb[i * 64] = kreg[i];
            if (i < nat) {
                const f4 kv = kreg[i];
                float ss = kv.x * q4.x + kv.y * q4.y + kv.z * q4.z + kv.w * q4.w;
                ss += __shfl_xor(ss, 1);
                ss += __shfl_xor(ss, 2);
                ss += __shfl_xor(ss, 4);
                ss += __shfl_xor(ss, 8);
                s[i] = (tl + i * 4 < slen) ? ss * QK_SCALE : -1e30f;
            }
        }
    } else {
#pragma unroll
        for (int i = 0; i < NWIN; ++i) {
            const int t = tl + i * 4;
            kreg[i] = (f4){0.f, 0.f, 0.f, 0.f};
            vreg[i] = (f4){0.f, 0.f, 0.f, 0.f};
            if (t < T_CACHE) {
                kreg[i] = kbase[i * 64];
                vreg[i] = vbase[i * 64];
            }
        }
#pragma unroll
        for (int i = 0; i < NWIN; ++i) {
            const int t = tl + i * 4;
            if (t < T_CACHE)
                Kb[i * 64] = kreg[i];
            if (i < nat) {
                const f4 kv = kreg[i];
                float ss = kv.x * q4.x + kv.y * q4.y + kv.z * q4.z + kv.w * q4.w;
                ss += __shfl_xor(ss, 1);
                ss += __shfl_xor(ss, 2);
                ss += __shfl_xor(ss, 4);
                ss += __shfl_xor(ss, 8);
                // token 2047 (the new token) is handled by combine_kernel
                s[i] = (t < slen && t < T_CACHE) ? ss * QK_SCALE : -1e30f;
            }
        }
    }

    // ---- softmax weights (exact wave max, single exp per window) ---------
    float m = -1e30f;
#pragma unroll
    for (int i = 0; i < NWIN; ++i)
        if (i < nat) m = fmaxf(m, s[i]);
    m = fmaxf(m, __shfl_xor(m, 16));
    m = fmaxf(m, __shfl_xor(m, 32));   // wave-uniform max

    float l = 0.f;
#pragma unroll
    for (int i = 0; i < NWIN; ++i)
        if (i < nat) {
            const float p = __expf(s[i] - m);   // masked: exp(-huge) == 0
            s[i] = p;
            l += p;
        }

    // ---- V: store + weighted accumulate ----------------------------------
    f4 o = {0.f, 0.f, 0.f, 0.f};
    if (!tail) {
#pragma unroll
        for (int i = 0; i < NWIN; ++i) {
            Vb[i * 64] = vreg[i];
            if (i < nat) {
                o.x = fmaf(s[i], vreg[i].x, o.x);
                o.y = fmaf(s[i], vreg[i].y, o.y);
                o.z = fmaf(s[i], vreg[i].z, o.z);
                o.w = fmaf(s[i], vreg[i].w, o.w);
            }
        }
    } else {
#pragma unroll
        for (int i = 0; i < NWIN; ++i) {
            const int t = tl + i * 4;
            if (t < T_CACHE)
                Vb[i * 64] = vreg[i];
            if (i < nat) {
                o.x = fmaf(s[i], vreg[i].x, o.x);
                o.y = fmaf(s[i], vreg[i].y, o.y);
                o.z = fmaf(s[i], vreg[i].z, o.z);
                o.w = fmaf(s[i], vreg[i].w, o.w);
            }
        }
    }

    // merge l and o across the 4 token groups within the wave
    l += __shfl_xor(l, 16); l += __shfl_xor(l, 32);
    o.x += __shfl_xor(o.x, 16); o.x += __shfl_xor(o.x, 32);
    o.y += __shfl_xor(o.y, 16); o.y += __shfl_xor(o.y, 32);
    o.z += __shfl_xor(o.z, 16); o.z += __shfl_xor(o.z, 32);
    o.w += __shfl_xor(o.w, 16); o.w += __shfl_xor(o.w, 32);

    // ---- block-level merge of the 4 wave partials ------------------------
    __shared__ float sm[4], sl[4];
    __shared__ f4 so4[4][16];
    if (lane == 0) { sm[wave] = m; sl[wave] = l; }
    if (lane < 16) so4[wave][dgrp] = o;
    __syncthreads();

    if (tid < HD) {
        const int d = tid;
        const float m0 = sm[0], m1 = sm[1], m2 = sm[2], m3 = sm[3];
        const float mc = fmaxf(fmaxf(m0, m1), fmaxf(m2, m3));
        const float e0 = __expf(m0 - mc), e1 = __expf(m1 - mc);
        const float e2 = __expf(m2 - mc), e3 = __expf(m3 - mc);
        const float lc = sl[0]*e0 + sl[1]*e1 + sl[2]*e2 + sl[3]*e3;
        const float* so = (const float*)so4;   // [4][64]
        const float oc = so[0*HD + d]*e0 + so[1*HD + d]*e1
                       + so[2*HD + d]*e2 + so[3*HD + d]*e3;
        const int pb = bh * NCHUNK + chunk;
        Po[(size_t)pb * HD + d] = oc;
        if (d == 0) { Pm[pb] = mc; Pl[pb] = lc; }
    }
}

// ---------------------------------------------------------------------------
// Combine chunk partials + the always-visible new token; also append the new
// k/v row to the output caches. q/k/v new-token values are reduced from the
// qkv partials inline (bit-identical order to a reduce kernel).
// grid = 512 (b*NH+h), block = 64 (one wave).
// ---------------------------------------------------------------------------
__global__ __launch_bounds__(64) void combine_kernel(
    const float* __restrict__ qkv_part, const float* __restrict__ b_attn,
    const float* __restrict__ Pm, const float* __restrict__ Pl,
    const float* __restrict__ Po,
    float* __restrict__ attn, float* __restrict__ Kout, float* __restrict__ Vout)
{
    const int bh = blockIdx.x;
    const int b = bh >> 4, h = bh & 15;
    const int d = threadIdx.x;     // 0..63

    float qd = b_attn[h * HD + d];
    float kn = b_attn[HID  + h * HD + d];
    float vn = b_attn[2*HID + h * HD + d];
#pragma unroll
    for (int ks = 0; ks < KSPLIT; ++ks) {
        const float* pp = qkv_part + ((size_t)ks * BATCH + b) * H3;
        qd += pp[h * HD + d];
        kn += pp[HID  + h * HD + d];
        vn += pp[2*HID + h * HD + d];
    }

    // append new token row (position T_ALL-1)
    Kout[((size_t)bh * T_ALL + (T_ALL - 1)) * HD + d] = kn;
    Vout[((size_t)bh * T_ALL + (T_ALL - 1)) * HD + d] = vn;

    // new-token score (always valid)
    float s = qd * kn;
    s += __shfl_xor(s, 1);
    s += __shfl_xor(s, 2);
    s += __shfl_xor(s, 4);
    s += __shfl_xor(s, 8);
    s += __shfl_xor(s, 16);
    s += __shfl_xor(s, 32);
    s *= QK_SCALE;

    float mg = s;
#pragma unroll 16
    for (int c = 0; c < NCHUNK; ++c)
        mg = fmaxf(mg, Pm[bh * NCHUNK + c]);

    float L   = __expf(s - mg);   // p_new
    float acc = L * vn;
#pragma unroll 8
    for (int c = 0; c < NCHUNK; ++c) {
        const float e = __expf(Pm[bh * NCHUNK + c] - mg);
        acc += Po[(size_t)(bh * NCHUNK + c) * HD + d] * e;
        L   += Pl[bh * NCHUNK + c] * e;
    }
    attn[(size_t)b * HID + h * HD + d] = acc / L;
}

// ---------------------------------------------------------------------------
extern "C" void kernel_launch(void* const* d_in, const int* in_sizes, int n_in,
                              void* d_out, int out_size, void* d_ws, size_t ws_size,
                              hipStream_t stream)
{
    const float* hs       = (const float*)d_in[0];   // [32,1,1024]
    const float* kc       = (const float*)d_in[1];   // [32,16,2047,64]
    const float* vc       = (const float*)d_in[2];   // [32,16,2047,64]
    // d_in[3] block_tables: unused by the reference math
    const int*   seq_lens = (const int*)d_in[4];     // [32]
    // d_in[5] max_seq_len: == 2048, hardcoded
    const float* W_attn   = (const float*)d_in[6];   // [1024,3072]
    const float* b_attn   = (const float*)d_in[7];   // [3072]
    const float* W_proj   = (const float*)d_in[8];   // [1024,1024]
    const float* b_proj   = (const float*)d_in[9];   // [1024]

    float* out_attn = (float*)d_out;                           // 32*1024
    float* Kout = out_attn + (size_t)BATCH * HID;              // 32*16*2048*64
    float* Vout = Kout + (size_t)BATCH * NH * T_ALL * HD;

    // workspace layout (floats)
    float* w = (float*)d_ws;
    float* w_qkv_part  = w;                                        // 786432
    float* w_Pm        = w_qkv_part + (size_t)KSPLIT * BATCH * H3; // 16384
    float* w_Pl        = w_Pm + BATCH * NH * NCHUNK;               // 16384
    float* w_Po        = w_Pl + BATCH * NH * NCHUNK;               // 1048576
    float* w_attnvec   = w_Po + (size_t)BATCH * NH * NCHUNK * HD;  // 32768
    float* w_proj_part = w_attnvec + (size_t)BATCH * HID;          // 262144
    // total ~2.16 M floats = 8.65 MB

    // 1) qkv partials (reduce is folded into consumers)
    gemv_part_kernel<16><<<dim3(H3 / 256, KSPLIT, 2), 256, 0, stream>>>(
        hs, W_attn, w_qkv_part, H3, HID);

    // 2) fused cache copy + flash-decoding chunks (q reduced inline)
    fused_copy_attn_kernel<<<dim3(NCHUNK, NH, BATCH), 256, 0, stream>>>(
        kc, vc, w_qkv_part, b_attn, seq_lens, Kout, Vout, w_Pm, w_Pl, w_Po);

    // 3) combine partials + new token, append new k/v rows
    combine_kernel<<<dim3(BATCH * NH), 64, 0, stream>>>(
        w_qkv_part, b_attn, w_Pm, w_Pl, w_Po, w_attnvec, Kout, Vout);

    // 4) out = attn @ W_proj + b_proj  (128 blocks, 8 batches/thread)
    gemv_part_kernel<8><<<dim3(HID / 256, KSPLIT, 4), 256, 0, stream>>>(
        w_attnvec, W_proj, w_proj_part, HID, HID);
    gemv_reduce_kernel<<<dim3(HID / 4 / 256, BATCH), 256, 0, stream>>>(
        w_proj_part, b_proj, out_attn, HID);
}

// Round 9
// 242.811 us; speedup vs baseline: 1.1232x; 1.1232x over previous
//
#include <hip/hip_runtime.h>
#include <math.h>

// Problem constants (GPT2 decode attention, fp32)
#define BATCH   32
#define NH      16
#define HD      64      // head dim
#define T_ALL   2048    // cached 2047 + 1 new
#define T_CACHE 2047
#define HID     1024
#define H3      3072
#define QK_SCALE 0.125f // 64^-0.5
#define NCHUNK  32      // token chunks per (b,h); one chunk per 4-wave block
#define CHTOK   64      // tokens per chunk (16 per wave)
#define NWIN    4       // 4-token windows per wave (16 tokens/wave)
#define KSPLIT  8       // k-split for the GEMV kernels

// native 16B vector
typedef float f4 __attribute__((ext_vector_type(4)));

// ---------------------------------------------------------------------------
// GEMV part: out_part[ks][b][c] = sum_{k in split ks} X[b][k] * W[k][c]
// batch split across blockIdx.z; per-column k-order unchanged -> bit-exact.
// ---------------------------------------------------------------------------
template<int NB>
__global__ __launch_bounds__(256) void gemv_part_kernel(
    const float* __restrict__ X, const float* __restrict__ W,
    float* __restrict__ part, int N, int Kdim)
{
    const int c  = blockIdx.x * 256 + threadIdx.x;
    const int ks = blockIdx.y;
    const int b0 = blockIdx.z * NB;
    const int kchunk = Kdim / KSPLIT;
    float acc[NB];
#pragma unroll
    for (int j = 0; j < NB; ++j) acc[j] = 0.f;
    const int k0 = ks * kchunk;
#pragma unroll 16
    for (int k = k0; k < k0 + kchunk; ++k) {
        const float w = W[(size_t)k * N + c];
#pragma unroll
        for (int j = 0; j < NB; ++j)
            acc[j] = fmaf(X[(b0 + j) * Kdim + k], w, acc[j]);
    }
#pragma unroll
    for (int j = 0; j < NB; ++j)
        part[((size_t)ks * BATCH + b0 + j) * N + c] = acc[j];
}

// float4 reduce (bit-exact per element: bias first, then ks ascending)
__global__ __launch_bounds__(256) void gemv_reduce_kernel(
    const float* __restrict__ part, const float* __restrict__ bias,
    float* __restrict__ out, int N)
{
    const int c4 = blockIdx.x * 256 + threadIdx.x;
    const int b  = blockIdx.y;
    const int N4 = N >> 2;
    f4 acc = ((const f4*)bias)[c4];
#pragma unroll
    for (int ks = 0; ks < KSPLIT; ++ks) {
        const f4 p = ((const f4*)part)[((size_t)ks * BATCH + b) * N4 + c4];
        acc.x += p.x; acc.y += p.y; acc.z += p.z; acc.w += p.w;
    }
    ((f4*)out)[(size_t)b * N4 + c4] = acc;
}

// ---------------------------------------------------------------------------
// Fused cache-copy + flash-decoding attention, v6 (r5 best: 243.2 us).
// grid = (NCHUNK=32, NH, BATCH) = 16384 blocks, block = 256 (4 waves).
// Wave owns 16 tokens = 4 windows (4 tokens x 16 f4-groups).
// NT hints on the K/V streams are REQUIRED: r8 A/B showed removing them
// costs +29.5 us (L2 no-allocate avoids write-allocate churn on the
// 1 GB one-touch stream).
// ---------------------------------------------------------------------------
__global__ __launch_bounds__(256, 6) void fused_copy_attn_kernel(
    const float* __restrict__ kc, const float* __restrict__ vc,
    const float* __restrict__ qkv_part, const float* __restrict__ b_attn,
    const int* __restrict__ seq_lens,
    float* __restrict__ Kout, float* __restrict__ Vout,
    float* __restrict__ Pm, float* __restrict__ Pl, float* __restrict__ Po)
{
    const int chunk = blockIdx.x;
    const int h     = blockIdx.y;
    const int b     = blockIdx.z;
    const int tid   = threadIdx.x;
    const int wave  = tid >> 6;
    const int lane  = tid & 63;
    const int dgrp  = lane & 15;   // which float4 of the 64-dim row
    const int tgrp  = lane >> 4;   // which of 4 tokens per window

    const int bh   = b * NH + h;
    const int slen = seq_lens[b];

    // q = b_attn + sum_ks qkv_part  (bit-identical to the removed reduce)
    f4 q4 = ((const f4*)(b_attn + h * HD))[dgrp];
#pragma unroll
    for (int ks = 0; ks < KSPLIT; ++ks) {
        const f4 p = ((const f4*)(qkv_part + ((size_t)ks * BATCH + b) * H3 + h * HD))[dgrp];
        q4.x += p.x; q4.y += p.y; q4.z += p.z; q4.w += p.w;
    }

    const int t0 = chunk * CHTOK + wave * (NWIN * 4);
    const int tl = t0 + tgrp;                       // this lane's first token
    const int nat  = min(NWIN, max(0, (slen - t0 + 3) >> 2));
    const bool tail = (t0 + NWIN * 4 - 1 >= T_CACHE);  // single tail wave

    const f4* kbase = (const f4*)(kc + (size_t)bh * T_CACHE * HD) + (size_t)tl * 16 + dgrp;
    const f4* vbase = (const f4*)(vc + (size_t)bh * T_CACHE * HD) + (size_t)tl * 16 + dgrp;
    f4* Kb = (f4*)(Kout + (size_t)bh * T_ALL * HD) + (size_t)tl * 16 + dgrp;
    f4* Vb = (f4*)(Vout + (size_t)bh * T_ALL * HD) + (size_t)tl * 16 + dgrp;

    f4 kreg[NWIN], vreg[NWIN];
    float s[NWIN];

    if (!tail) {
        // ---- issue ALL loads upfront: 8 in flight per wave ---------------
#pragma unroll
        for (int i = 0; i < NWIN; ++i)
            kreg[i] = __builtin_nontemporal_load(kbase + i * 64);
#pragma unroll
        for (int i = 0; i < NWIN; ++i)
            vreg[i] = __builtin_nontemporal_load(vbase + i * 64);

        // ---- K: store + scores (V loads still in flight) -----------------
#pragma unroll
        for (int i = 0; i < NWIN; ++i) {
            __builtin_nontemporal_store(kreg[i], Kb + i * 64);
            if (i < nat) {
                const f4 kv = kreg[i];
                float ss = kv.x * q4.x + kv.y * q4.y + kv.z * q4.z + kv.w * q4.w;
                ss += __shfl_xor(ss, 1);
                ss += __shfl_xor(ss, 2);
                ss += __shfl_xor(ss, 4);
                ss += __shfl_xor(ss, 8);
                s[i] = (tl + i * 4 < slen) ? ss * QK_SCALE : -1e30f;
            }
        }
    } else {
#pragma unroll
        for (int i = 0; i < NWIN; ++i) {
            const int t = tl + i * 4;
            kreg[i] = (f4){0.f, 0.f, 0.f, 0.f};
            vreg[i] = (f4){0.f, 0.f, 0.f, 0.f};
            if (t < T_CACHE) {
                kreg[i] = __builtin_nontemporal_load(kbase + i * 64);
                vreg[i] = __builtin_nontemporal_load(vbase + i * 64);
            }
        }
#pragma unroll
        for (int i = 0; i < NWIN; ++i) {
            const int t = tl + i * 4;
            if (t < T_CACHE)
                __builtin_nontemporal_store(kreg[i], Kb + i * 64);
            if (i < nat) {
                const f4 kv = kreg[i];
                float ss = kv.x * q4.x + kv.y * q4.y + kv.z * q4.z + kv.w * q4.w;
                ss += __shfl_xor(ss, 1);
                ss += __shfl_xor(ss, 2);
                ss += __shfl_xor(ss, 4);
                ss += __shfl_xor(ss, 8);
                // token 2047 (the new token) is handled by combine_kernel
                s[i] = (t < slen && t < T_CACHE) ? ss * QK_SCALE : -1e30f;
            }
        }
    }

    // ---- softmax weights (exact wave max, single exp per window) ---------
    float m = -1e30f;
#pragma unroll
    for (int i = 0; i < NWIN; ++i)
        if (i < nat) m = fmaxf(m, s[i]);
    m = fmaxf(m, __shfl_xor(m, 16));
    m = fmaxf(m, __shfl_xor(m, 32));   // wave-uniform max

    float l = 0.f;
#pragma unroll
    for (int i = 0; i < NWIN; ++i)
        if (i < nat) {
            const float p = __expf(s[i] - m);   // masked: exp(-huge) == 0
            s[i] = p;
            l += p;
        }

    // ---- V: store + weighted accumulate ----------------------------------
    f4 o = {0.f, 0.f, 0.f, 0.f};
    if (!tail) {
#pragma unroll
        for (int i = 0; i < NWIN; ++i) {
            __builtin_nontemporal_store(vreg[i], Vb + i * 64);
            if (i < nat) {
                o.x = fmaf(s[i], vreg[i].x, o.x);
                o.y = fmaf(s[i], vreg[i].y, o.y);
                o.z = fmaf(s[i], vreg[i].z, o.z);
                o.w = fmaf(s[i], vreg[i].w, o.w);
            }
        }
    } else {
#pragma unroll
        for (int i = 0; i < NWIN; ++i) {
            const int t = tl + i * 4;
            if (t < T_CACHE)
                __builtin_nontemporal_store(vreg[i], Vb + i * 64);
            if (i < nat) {
                o.x = fmaf(s[i], vreg[i].x, o.x);
                o.y = fmaf(s[i], vreg[i].y, o.y);
                o.z = fmaf(s[i], vreg[i].z, o.z);
                o.w = fmaf(s[i], vreg[i].w, o.w);
            }
        }
    }

    // merge l and o across the 4 token groups within the wave
    l += __shfl_xor(l, 16); l += __shfl_xor(l, 32);
    o.x += __shfl_xor(o.x, 16); o.x += __shfl_xor(o.x, 32);
    o.y += __shfl_xor(o.y, 16); o.y += __shfl_xor(o.y, 32);
    o.z += __shfl_xor(o.z, 16); o.z += __shfl_xor(o.z, 32);
    o.w += __shfl_xor(o.w, 16); o.w += __shfl_xor(o.w, 32);

    // ---- block-level merge of the 4 wave partials ------------------------
    __shared__ float sm[4], sl[4];
    __shared__ f4 so4[4][16];
    if (lane == 0) { sm[wave] = m; sl[wave] = l; }
    if (lane < 16) so4[wave][dgrp] = o;
    __syncthreads();

    if (tid < HD) {
        const int d = tid;
        const float m0 = sm[0], m1 = sm[1], m2 = sm[2], m3 = sm[3];
        const float mc = fmaxf(fmaxf(m0, m1), fmaxf(m2, m3));
        const float e0 = __expf(m0 - mc), e1 = __expf(m1 - mc);
        const float e2 = __expf(m2 - mc), e3 = __expf(m3 - mc);
        const float lc = sl[0]*e0 + sl[1]*e1 + sl[2]*e2 + sl[3]*e3;
        const float* so = (const float*)so4;   // [4][64]
        const float oc = so[0*HD + d]*e0 + so[1*HD + d]*e1
                       + so[2*HD + d]*e2 + so[3*HD + d]*e3;
        const int pb = bh * NCHUNK + chunk;
        Po[(size_t)pb * HD + d] = oc;
        if (d == 0) { Pm[pb] = mc; Pl[pb] = lc; }
    }
}

// ---------------------------------------------------------------------------
// Combine chunk partials + the always-visible new token; also append the new
// k/v row to the output caches. q/k/v new-token values are reduced from the
// qkv partials inline (bit-identical order to a reduce kernel).
// grid = 512 (b*NH+h), block = 64 (one wave).
// ---------------------------------------------------------------------------
__global__ __launch_bounds__(64) void combine_kernel(
    const float* __restrict__ qkv_part, const float* __restrict__ b_attn,
    const float* __restrict__ Pm, const float* __restrict__ Pl,
    const float* __restrict__ Po,
    float* __restrict__ attn, float* __restrict__ Kout, float* __restrict__ Vout)
{
    const int bh = blockIdx.x;
    const int b = bh >> 4, h = bh & 15;
    const int d = threadIdx.x;     // 0..63

    float qd = b_attn[h * HD + d];
    float kn = b_attn[HID  + h * HD + d];
    float vn = b_attn[2*HID + h * HD + d];
#pragma unroll
    for (int ks = 0; ks < KSPLIT; ++ks) {
        const float* pp = qkv_part + ((size_t)ks * BATCH + b) * H3;
        qd += pp[h * HD + d];
        kn += pp[HID  + h * HD + d];
        vn += pp[2*HID + h * HD + d];
    }

    // append new token row (position T_ALL-1)
    Kout[((size_t)bh * T_ALL + (T_ALL - 1)) * HD + d] = kn;
    Vout[((size_t)bh * T_ALL + (T_ALL - 1)) * HD + d] = vn;

    // new-token score (always valid)
    float s = qd * kn;
    s += __shfl_xor(s, 1);
    s += __shfl_xor(s, 2);
    s += __shfl_xor(s, 4);
    s += __shfl_xor(s, 8);
    s += __shfl_xor(s, 16);
    s += __shfl_xor(s, 32);
    s *= QK_SCALE;

    float mg = s;
#pragma unroll 16
    for (int c = 0; c < NCHUNK; ++c)
        mg = fmaxf(mg, Pm[bh * NCHUNK + c]);

    float L   = __expf(s - mg);   // p_new
    float acc = L * vn;
#pragma unroll 8
    for (int c = 0; c < NCHUNK; ++c) {
        const float e = __expf(Pm[bh * NCHUNK + c] - mg);
        acc += Po[(size_t)(bh * NCHUNK + c) * HD + d] * e;
        L   += Pl[bh * NCHUNK + c] * e;
    }
    attn[(size_t)b * HID + h * HD + d] = acc / L;
}

// ---------------------------------------------------------------------------
extern "C" void kernel_launch(void* const* d_in, const int* in_sizes, int n_in,
                              void* d_out, int out_size, void* d_ws, size_t ws_size,
                              hipStream_t stream)
{
    const float* hs       = (const float*)d_in[0];   // [32,1,1024]
    const float* kc       = (const float*)d_in[1];   // [32,16,2047,64]
    const float* vc       = (const float*)d_in[2];   // [32,16,2047,64]
    // d_in[3] block_tables: unused by the reference math
    const int*   seq_lens = (const int*)d_in[4];     // [32]
    // d_in[5] max_seq_len: == 2048, hardcoded
    const float* W_attn   = (const float*)d_in[6];   // [1024,3072]
    const float* b_attn   = (const float*)d_in[7];   // [3072]
    const float* W_proj   = (const float*)d_in[8];   // [1024,1024]
    const float* b_proj   = (const float*)d_in[9];   // [1024]

    float* out_attn = (float*)d_out;                           // 32*1024
    float* Kout = out_attn + (size_t)BATCH * HID;              // 32*16*2048*64
    float* Vout = Kout + (size_t)BATCH * NH * T_ALL * HD;

    // workspace layout (floats)
    float* w = (float*)d_ws;
    float* w_qkv_part  = w;                                        // 786432
    float* w_Pm        = w_qkv_part + (size_t)KSPLIT * BATCH * H3; // 16384
    float* w_Pl        = w_Pm + BATCH * NH * NCHUNK;               // 16384
    float* w_Po        = w_Pl + BATCH * NH * NCHUNK;               // 1048576
    float* w_attnvec   = w_Po + (size_t)BATCH * NH * NCHUNK * HD;  // 32768
    float* w_proj_part = w_attnvec + (size_t)BATCH * HID;          // 262144
    // total ~2.16 M floats = 8.65 MB

    // 1) qkv partials (reduce is folded into consumers)
    gemv_part_kernel<16><<<dim3(H3 / 256, KSPLIT, 2), 256, 0, stream>>>(
        hs, W_attn, w_qkv_part, H3, HID);

    // 2) fused cache copy + flash-decoding chunks (q reduced inline)
    fused_copy_attn_kernel<<<dim3(NCHUNK, NH, BATCH), 256, 0, stream>>>(
        kc, vc, w_qkv_part, b_attn, seq_lens, Kout, Vout, w_Pm, w_Pl, w_Po);

    // 3) combine partials + new token, append new k/v rows
    combine_kernel<<<dim3(BATCH * NH), 64, 0, stream>>>(
        w_qkv_part, b_attn, w_Pm, w_Pl, w_Po, w_attnvec, Kout, Vout);

    // 4) out = attn @ W_proj + b_proj  (128 blocks, 8 batches/thread)
    gemv_part_kernel<8><<<dim3(HID / 256, KSPLIT, 4), 256, 0, stream>>>(
        w_attnvec, W_proj, w_proj_part, HID, HID);
    gemv_reduce_kernel<<<dim3(HID / 4 / 256, BATCH), 256, 0, stream>>>(
        w_proj_part, b_proj, out_attn, HID);
}